// Round 12
// baseline (1479.934 us; speedup 1.0000x reference)
//
#include <hip/hip_runtime.h>

#define N_ENT 50000
#define H 128
#define NREL 460
#define T_STEPS 8
#define NEDGE 600000
#define SLOPE 0.22916666666666666f
#define NBUK 391   // ceil(N_ENT/128)
#define EPB 4096   // edges per passA block

typedef __attribute__((ext_vector_type(8))) short bf16x8;
typedef __attribute__((ext_vector_type(8))) unsigned short us8;
typedef __attribute__((ext_vector_type(4))) float f32x4;
typedef unsigned short u16;
typedef unsigned int u32;
typedef unsigned long long u64;

__device__ __forceinline__ float b2f(u16 u) {
  union { u32 i; float f; } v; v.i = ((u32)u) << 16; return v.f;
}
__device__ __forceinline__ u16 f2b(float f) {
  union { float f; u32 i; } v; v.f = f;
  return (u16)((v.i + 0x7FFFu + ((v.i >> 16) & 1u)) >> 16);
}
__device__ __forceinline__ float wave_sum(float v) {
#pragma unroll
  for (int off = 32; off > 0; off >>= 1) v += __shfl_xor(v, off, 64);
  return v;
}

// ---------- weight prep: bf16 transposed [n][k], 5 matrices ----------
__global__ void convw_kernel(const float* __restrict__ wn, const float* __restrict__ wl,
                             const float* __restrict__ tg, u16* __restrict__ wbt) {
  int m = blockIdx.x >> 6;
  int f = ((blockIdx.x & 63) << 8) + threadIdx.x;
  int n = f >> 7, k = f & 127;
  const float* src;
  switch (m) {
    case 0: src = wn; break;          // w_neigh[0]
    case 1: src = wl; break;          // w_loop[0]
    case 2: src = wn + 16384; break;  // w_neigh[1]
    case 3: src = wl + 16384; break;  // w_loop[1]
    default: src = tg; break;         // tg_w
  }
  wbt[m * 16384 + n * 128 + k] = f2b(src[k * 128 + n]);
}

// rel table f32 -> bf16
__global__ void convrel_kernel(const float* __restrict__ rel, u16* __restrict__ relb) {
  int i = blockIdx.x * 256 + threadIdx.x;  // 230*256 == 58880 exactly
  relb[i] = f2b(rel[i]);
}

// ---------- h0 = l2norm(emb_ent), f32 + bf16 ----------
__global__ void l2norm_kernel(const float* __restrict__ in, float* __restrict__ out,
                              u16* __restrict__ outb) {
  int row = blockIdx.x * 4 + (threadIdx.x >> 6);
  int lane = threadIdx.x & 63;
  size_t base = (size_t)row * H;
  float2 v = ((const float2*)(in + base))[lane];
  float ss = wave_sum(v.x * v.x + v.y * v.y);
  float inv = 1.0f / fmaxf(sqrtf(ss), 1e-12f);
  float2 o = {v.x * inv, v.y * inv};
  ((float2*)(out + base))[lane] = o;
  ushort2 ob; ob.x = f2b(o.x); ob.y = f2b(o.y);
  ((ushort2*)(outb + base))[lane] = ob;
}

// ---------- bucketed CSR build ----------
__global__ __launch_bounds__(256) void bucket_count(const int* __restrict__ dst,
                                                    int* __restrict__ bcnt) {
  int t = blockIdx.y;
  __shared__ int lc[NBUK];
  for (int j = threadIdx.x; j < NBUK; j += 256) lc[j] = 0;
  __syncthreads();
  for (int i = blockIdx.x * 256 + threadIdx.x; i < NEDGE; i += 64 * 256)
    atomicAdd(&lc[dst[(size_t)t * NEDGE + i] >> 7], 1);
  __syncthreads();
  for (int j = threadIdx.x; j < NBUK; j += 256)
    if (lc[j]) atomicAdd(&bcnt[t * NBUK + j], lc[j]);
}

__global__ __launch_bounds__(512) void bucket_scan(const int* __restrict__ bcnt,
                                                   int* __restrict__ bstart,
                                                   int* __restrict__ curA) {
  int t = blockIdx.x, tid = threadIdx.x;
  __shared__ int s[512];
  int v = (tid < NBUK) ? bcnt[t * NBUK + tid] : 0;
  s[tid] = v;
  __syncthreads();
  for (int off = 1; off < 512; off <<= 1) {
    int u = (tid >= off) ? s[tid - off] : 0;
    __syncthreads();
    s[tid] += u;
    __syncthreads();
  }
  if (tid < NBUK) {
    int ex = s[tid] - v;
    bstart[t * NBUK + tid] = ex;
    curA[t * NBUK + tid] = ex;
  }
}

// pass A (two-level): LDS bucket histogram -> chunked global reservation ->
// mostly-coalesced 4B scatter. Entry pack: src(16) | ety<<16 (9) | (d&127)<<25 (7).
__global__ __launch_bounds__(256) void passA_kernel(const int* __restrict__ src,
                                                    const int* __restrict__ dst,
                                                    const int* __restrict__ ety,
                                                    int* curA, u32* __restrict__ tmp) {
  int t = blockIdx.y;
  __shared__ int cnt[NBUK], base[NBUK];
  for (int j = threadIdx.x; j < NBUK; j += 256) cnt[j] = 0;
  __syncthreads();
  int e0 = blockIdx.x * EPB;
  int e1 = e0 + EPB < NEDGE ? e0 + EPB : NEDGE;
  for (int i = e0 + threadIdx.x; i < e1; i += 256)
    atomicAdd(&cnt[dst[(size_t)t * NEDGE + i] >> 7], 1);
  __syncthreads();
  for (int j = threadIdx.x; j < NBUK; j += 256) {
    int c = cnt[j];
    base[j] = c ? atomicAdd(&curA[t * NBUK + j], c) : 0;
    cnt[j] = 0;  // becomes local cursor
  }
  __syncthreads();
  for (int i = e0 + threadIdx.x; i < e1; i += 256) {
    size_t o = (size_t)t * NEDGE + i;
    int d = dst[o];
    int j = d >> 7;
    int p = base[j] + atomicAdd(&cnt[j], 1);
    tmp[(size_t)t * NEDGE + p] =
        (u32)src[o] | ((u32)ety[o] << 16) | ((u32)(d & 127) << 25);
  }
}

// pass B: one block per (bucket, t); per-dst counts+scan in LDS, write rp ends,
// scatter final 4B entries (top 7 bits stripped) within the bucket's window
__global__ __launch_bounds__(256) void passB_kernel(const u32* __restrict__ tmp,
                                                    const int* __restrict__ bstart,
                                                    int* __restrict__ rp,
                                                    u32* __restrict__ edges) {
  int t = blockIdx.y, b = blockIdx.x, tid = threadIdx.x;
  int start = bstart[t * NBUK + b];
  int end = (b + 1 < NBUK) ? bstart[t * NBUK + b + 1] : NEDGE;
  __shared__ int cnt[128], scn[128], cur[128];
  if (tid < 128) cnt[tid] = 0;
  __syncthreads();
  for (int i = start + tid; i < end; i += 256)
    atomicAdd(&cnt[(int)(tmp[(size_t)t * NEDGE + i] >> 25)], 1);
  __syncthreads();
  if (tid < 128) scn[tid] = cnt[tid];
  __syncthreads();
  for (int off = 1; off < 128; off <<= 1) {
    int u = (tid < 128 && tid >= off) ? scn[tid - off] : 0;
    __syncthreads();
    if (tid < 128) scn[tid] += u;
    __syncthreads();
  }
  if (tid < 128) {
    int rs = start + scn[tid] - cnt[tid];
    cur[tid] = rs;
    int gd = (b << 7) + tid;
    if (gd < N_ENT) rp[t * N_ENT + gd] = rs + cnt[tid];  // end-of-row
  }
  __syncthreads();
  for (int i = start + tid; i < end; i += 256) {
    u32 e = tmp[(size_t)t * NEDGE + i];
    int p = atomicAdd(&cur[(int)(e >> 25)], 1);
    edges[(size_t)t * NEDGE + p] = e & 0x1FFFFFFu;  // src | ety<<16
  }
}

// ---------- agg[d] = (sum h[src]+rel[ty]) / max(deg,1), bf16 in/out ----------
// 16 lanes x ushort8 per row: 4 rows per wave, 8 outstanding 16B loads per lane
__global__ __launch_bounds__(256) void gather_kernel(const u16* __restrict__ hb,
                                                     const u16* __restrict__ relb,
                                                     const int* __restrict__ rp,
                                                     const u32* __restrict__ edges,
                                                     u16* __restrict__ aggb) {
  int d = blockIdx.x * 16 + (threadIdx.x >> 4);
  int q = threadIdx.x & 15;
  int start = d ? rp[d - 1] : 0, end = rp[d];
  float a[8] = {};
  int i = start;
  for (; i + 4 <= end; i += 4) {
    u32 e0 = edges[i], e1 = edges[i + 1], e2 = edges[i + 2], e3 = edges[i + 3];
    us8 h0 = *(const us8*)(hb + (size_t)(e0 & 0xFFFF) * H + q * 8);
    us8 r0 = *(const us8*)(relb + (size_t)(e0 >> 16) * H + q * 8);
    us8 h1 = *(const us8*)(hb + (size_t)(e1 & 0xFFFF) * H + q * 8);
    us8 r1 = *(const us8*)(relb + (size_t)(e1 >> 16) * H + q * 8);
    us8 h2 = *(const us8*)(hb + (size_t)(e2 & 0xFFFF) * H + q * 8);
    us8 r2 = *(const us8*)(relb + (size_t)(e2 >> 16) * H + q * 8);
    us8 h3 = *(const us8*)(hb + (size_t)(e3 & 0xFFFF) * H + q * 8);
    us8 r3 = *(const us8*)(relb + (size_t)(e3 >> 16) * H + q * 8);
#pragma unroll
    for (int j = 0; j < 8; j++)
      a[j] += (b2f(h0[j]) + b2f(r0[j])) + (b2f(h1[j]) + b2f(r1[j])) +
              (b2f(h2[j]) + b2f(r2[j])) + (b2f(h3[j]) + b2f(r3[j]));
  }
  for (; i < end; i++) {
    u32 e0 = edges[i];
    us8 h0 = *(const us8*)(hb + (size_t)(e0 & 0xFFFF) * H + q * 8);
    us8 r0 = *(const us8*)(relb + (size_t)(e0 >> 16) * H + q * 8);
#pragma unroll
    for (int j = 0; j < 8; j++) a[j] += b2f(h0[j]) + b2f(r0[j]);
  }
  int deg = end - start;
  float nm = 1.0f / (float)(deg > 0 ? deg : 1);
  us8 o;
#pragma unroll
  for (int j = 0; j < 8; j++) o[j] = f2b(a[j] * nm);
  *(us8*)(aggb + (size_t)d * H + q * 8) = o;
}

// ---------- layer-0: hA = rrelu(agg@Wn0 + h@Wl0), bf16 out ----------
// deg==0 rows (agg==0) are recomputed inline as rrelu(h@We0) [folded fixup]
__global__ __launch_bounds__(256) void rgcn_gemm0(
    const u16* __restrict__ A1, const u16* __restrict__ A2,
    const u16* __restrict__ B1t, const u16* __restrict__ B2t,
    const float* __restrict__ We, const int* __restrict__ rp,
    u16* __restrict__ Cb) {
  int wave = threadIdx.x >> 6, lane = threadIdx.x & 63;
  int row0 = blockIdx.x * 64 + wave * 16;
  int ar = lane & 15, kg = lane >> 4;
  int arow = row0 + ar;
  if (arow >= N_ENT) arow = N_ENT - 1;
  bf16x8 a1[4], a2[4];
#pragma unroll
  for (int s = 0; s < 4; s++) {
    a1[s] = *(const bf16x8*)(A1 + (size_t)arow * H + s * 32 + kg * 8);
    a2[s] = *(const bf16x8*)(A2 + (size_t)arow * H + s * 32 + kg * 8);
  }
  f32x4 acc[8];
  f32x4 z = {0.f, 0.f, 0.f, 0.f};
#pragma unroll
  for (int n = 0; n < 8; n++) acc[n] = z;
#pragma unroll
  for (int n = 0; n < 8; n++) {
    const u16* b1p = B1t + (size_t)(n * 16 + ar) * H + kg * 8;
    const u16* b2p = B2t + (size_t)(n * 16 + ar) * H + kg * 8;
#pragma unroll
    for (int s = 0; s < 4; s++) {
      bf16x8 b1 = *(const bf16x8*)(b1p + s * 32);
      bf16x8 b2 = *(const bf16x8*)(b2p + s * 32);
      acc[n] = __builtin_amdgcn_mfma_f32_16x16x32_bf16(a1[s], b1, acc[n], 0, 0, 0);
      acc[n] = __builtin_amdgcn_mfma_f32_16x16x32_bf16(a2[s], b2, acc[n], 0, 0, 0);
    }
  }
#pragma unroll
  for (int r = 0; r < 4; r++) {
    int gr = row0 + kg * 4 + r;
    if (gr >= N_ENT) continue;
    int dg = rp[gr] - (gr ? rp[gr - 1] : 0);
    if (dg == 0) {  // rare: recompute rrelu(h @ We) for this row's 8 cols
      float s[8] = {};
      for (int k = 0; k < H; k++) {
        float hv = b2f(A2[(size_t)gr * H + k]);
#pragma unroll
        for (int n = 0; n < 8; n++)
          s[n] = fmaf(hv, We[(size_t)k * H + ar + n * 16], s[n]);
      }
#pragma unroll
      for (int n = 0; n < 8; n++) {
        float v = s[n] >= 0.f ? s[n] : SLOPE * s[n];
        Cb[(size_t)gr * H + ar + n * 16] = f2b(v);
      }
    } else {
#pragma unroll
      for (int n = 0; n < 8; n++) {
        float v = acc[n][r];
        v = v >= 0.f ? v : SLOPE * v;
        Cb[(size_t)gr * H + ar + n * 16] = f2b(v);
      }
    }
  }
}

// ---------- fused layer-1 GEMM + gate GEMM + rrelu + l2norm + combine ----------
// deg==0 rows recompute z = rrelu(hA@We1) inline before the l2norm [folded fixup]
__global__ __launch_bounds__(256) void step_final(
    const u16* __restrict__ aggb, const u16* __restrict__ hAb, const u16* hbio,
    const u16* __restrict__ B1t, const u16* __restrict__ B2t, const u16* __restrict__ B3t,
    const float* __restrict__ We, const int* __restrict__ rp,
    const float* __restrict__ tgb, const float* __restrict__ h_t, float* __restrict__ h_n,
    u16* hb_out) {
  int wave = threadIdx.x >> 6, lane = threadIdx.x & 63;
  int row0 = blockIdx.x * 64 + wave * 16;
  int ar = lane & 15, kg = lane >> 4;
  int arow = row0 + ar;
  if (arow >= N_ENT) arow = N_ENT - 1;
  bf16x8 a1[4], a2[4], a3[4];
#pragma unroll
  for (int s = 0; s < 4; s++) {
    a1[s] = *(const bf16x8*)(aggb + (size_t)arow * H + s * 32 + kg * 8);
    a2[s] = *(const bf16x8*)(hAb + (size_t)arow * H + s * 32 + kg * 8);
    a3[s] = *(const bf16x8*)(hbio + (size_t)arow * H + s * 32 + kg * 8);
  }
  f32x4 accm[8], accg[8];
  f32x4 z4 = {0.f, 0.f, 0.f, 0.f};
#pragma unroll
  for (int n = 0; n < 8; n++) { accm[n] = z4; accg[n] = z4; }
#pragma unroll
  for (int n = 0; n < 8; n++) {
    const u16* b1p = B1t + (size_t)(n * 16 + ar) * H + kg * 8;
    const u16* b2p = B2t + (size_t)(n * 16 + ar) * H + kg * 8;
    const u16* b3p = B3t + (size_t)(n * 16 + ar) * H + kg * 8;
#pragma unroll
    for (int s = 0; s < 4; s++) {
      bf16x8 b1 = *(const bf16x8*)(b1p + s * 32);
      bf16x8 b2 = *(const bf16x8*)(b2p + s * 32);
      bf16x8 b3 = *(const bf16x8*)(b3p + s * 32);
      accm[n] = __builtin_amdgcn_mfma_f32_16x16x32_bf16(a1[s], b1, accm[n], 0, 0, 0);
      accm[n] = __builtin_amdgcn_mfma_f32_16x16x32_bf16(a2[s], b2, accm[n], 0, 0, 0);
      accg[n] = __builtin_amdgcn_mfma_f32_16x16x32_bf16(a3[s], b3, accg[n], 0, 0, 0);
    }
  }
#pragma unroll
  for (int r = 0; r < 4; r++) {
    int grow = row0 + kg * 4 + r;
    bool ok = grow < N_ENT;
    int gsafe = ok ? grow : 0;
    int dg = ok ? (rp[gsafe] - (gsafe ? rp[gsafe - 1] : 0)) : 1;
    float zs[8], ssq = 0.f;
    if (dg == 0) {  // rare: z = rrelu(hA @ We1)
#pragma unroll
      for (int n = 0; n < 8; n++) zs[n] = 0.f;
      for (int k = 0; k < H; k++) {
        float hv = b2f(hAb[(size_t)grow * H + k]);
#pragma unroll
        for (int n = 0; n < 8; n++)
          zs[n] = fmaf(hv, We[(size_t)k * H + ar + n * 16], zs[n]);
      }
#pragma unroll
      for (int n = 0; n < 8; n++) {
        zs[n] = zs[n] >= 0.f ? zs[n] : SLOPE * zs[n];
        ssq += zs[n] * zs[n];
      }
    } else {
#pragma unroll
      for (int n = 0; n < 8; n++) {
        float v = accm[n][r];
        v = v >= 0.f ? v : SLOPE * v;
        zs[n] = v;
        ssq += v * v;
      }
    }
    ssq += __shfl_xor(ssq, 1, 64);
    ssq += __shfl_xor(ssq, 2, 64);
    ssq += __shfl_xor(ssq, 4, 64);
    ssq += __shfl_xor(ssq, 8, 64);
    float inv = 1.0f / fmaxf(sqrtf(ssq), 1e-12f);
#pragma unroll
    for (int n = 0; n < 8; n++) {
      int c = ar + n * 16;
      float g = 1.0f / (1.0f + expf(-(accg[n][r] + tgb[c])));
      float hp = ok ? h_t[(size_t)grow * H + c] : 0.f;
      float o = g * (zs[n] * inv) + (1.0f - g) * hp;
      if (ok) {
        h_n[(size_t)grow * H + c] = o;
        hb_out[(size_t)grow * H + c] = f2b(o);
      }
    }
  }
}

extern "C" void kernel_launch(void* const* d_in, const int* in_sizes, int n_in,
                              void* d_out, int out_size, void* d_ws, size_t ws_size,
                              hipStream_t stream) {
  const float* emb_ent  = (const float*)d_in[0];
  const float* emb_rel  = (const float*)d_in[1];
  const float* w_neigh  = (const float*)d_in[2];
  const float* w_loop   = (const float*)d_in[3];
  const float* w_evolve = (const float*)d_in[4];
  const float* tg_w     = (const float*)d_in[5];
  const float* tg_b     = (const float*)d_in[6];
  const int* src = (const int*)d_in[7];
  const int* dst = (const int*)d_in[8];
  const int* ety = (const int*)d_in[9];
  float* out = (float*)d_out;

  const size_t NH = (size_t)N_ENT * H;
  auto au = [](size_t x) { return (x + 255) & ~(size_t)255; };
  char* w = (char*)d_ws;
  int* rp8 = (int*)w;     w += au((size_t)T_STEPS * N_ENT * 4);
  int* bcnt = (int*)w;    w += au((size_t)T_STEPS * NBUK * 4);
  int* bstart = (int*)w;  w += au((size_t)T_STEPS * NBUK * 4);
  int* curA = (int*)w;    w += au((size_t)T_STEPS * NBUK * 4);
  u32* edges8 = (u32*)w;  w += au((size_t)T_STEPS * NEDGE * 4);
  // union: tmp (8*NEDGE*4 = 19.2MB) aliases aggb|hAb|hb (3*NH*2 = 38.4MB).
  // CSR build (writes+reads tmp) fully precedes l2norm (first hb write).
  char* uni = w;          w += au(NH * 6);
  u32* tmp = (u32*)uni;
  u16* aggb = (u16*)uni;
  u16* hAb = (u16*)(uni + NH * 2);
  u16* hb  = (u16*)(uni + NH * 4);
  u16* wbt = (u16*)w;     w += au((size_t)5 * 16384 * 2);
  u16* relb = (u16*)w;    w += au((size_t)NREL * H * 2);

  // ---- CSR build first (uses tmp region before aggb/hAb/hb alias it) ----
  hipMemsetAsync(bcnt, 0, (size_t)T_STEPS * NBUK * 4, stream);
  bucket_count<<<dim3(64, T_STEPS), 256, 0, stream>>>(dst, bcnt);
  bucket_scan<<<T_STEPS, 512, 0, stream>>>(bcnt, bstart, curA);
  passA_kernel<<<dim3((NEDGE + EPB - 1) / EPB, T_STEPS), 256, 0, stream>>>(
      src, dst, ety, curA, tmp);
  passB_kernel<<<dim3(NBUK, T_STEPS), 256, 0, stream>>>(tmp, bstart, rp8, edges8);

  // ---- conversions + h0 (hb now safe to write) ----
  hipMemcpyAsync(out + (size_t)(T_STEPS + 1) * NH, emb_rel, (size_t)NREL * H * 4,
                 hipMemcpyDeviceToDevice, stream);
  convw_kernel<<<320, 256, 0, stream>>>(w_neigh, w_loop, tg_w, wbt);
  convrel_kernel<<<230, 256, 0, stream>>>(emb_rel, relb);
  l2norm_kernel<<<N_ENT / 4, 256, 0, stream>>>(emb_ent, out, hb);

  for (int t = 0; t < T_STEPS; t++) {
    float* h_t = out + (size_t)t * NH;
    float* h_n = out + (size_t)(t + 1) * NH;
    const int* rp = rp8 + (size_t)t * N_ENT;
    const u32* edges = edges8 + (size_t)t * NEDGE;

    // layer 0 (fixup folded into epilogue)
    gather_kernel<<<N_ENT / 16, 256, 0, stream>>>(hb, relb, rp, edges, aggb);
    rgcn_gemm0<<<(N_ENT + 63) / 64, 256, 0, stream>>>(
        aggb, hb, wbt, wbt + 16384, w_evolve, rp, hAb);
    // layer 1 + gate + l2norm + combine (fixup folded)
    gather_kernel<<<N_ENT / 16, 256, 0, stream>>>(hAb, relb, rp, edges, aggb);
    step_final<<<(N_ENT + 63) / 64, 256, 0, stream>>>(
        aggb, hAb, hb, wbt + 32768, wbt + 49152, wbt + 65536,
        w_evolve + 16384, rp, tg_b, h_t, h_n, hb);
  }
}

// Round 13
// 1435.250 us; speedup vs baseline: 1.0311x; 1.0311x over previous
//
#include <hip/hip_runtime.h>

#define N_ENT 50000
#define H 128
#define NREL 460
#define T_STEPS 8
#define NEDGE 600000
#define SLOPE 0.22916666666666666f
#define NBUK 391   // ceil(N_ENT/128)
#define EPB 4096   // edges per passA block

typedef __attribute__((ext_vector_type(8))) short bf16x8;
typedef __attribute__((ext_vector_type(8))) unsigned short us8;
typedef __attribute__((ext_vector_type(4))) float f32x4;
typedef unsigned short u16;
typedef unsigned int u32;
typedef unsigned long long u64;

__device__ __forceinline__ float b2f(u16 u) {
  union { u32 i; float f; } v; v.i = ((u32)u) << 16; return v.f;
}
__device__ __forceinline__ u16 f2b(float f) {
  union { float f; u32 i; } v; v.f = f;
  return (u16)((v.i + 0x7FFFu + ((v.i >> 16) & 1u)) >> 16);
}
__device__ __forceinline__ float wave_sum(float v) {
#pragma unroll
  for (int off = 32; off > 0; off >>= 1) v += __shfl_xor(v, off, 64);
  return v;
}

// ---------- weight prep: bf16 transposed [n][k], 5 matrices ----------
__global__ void convw_kernel(const float* __restrict__ wn, const float* __restrict__ wl,
                             const float* __restrict__ tg, u16* __restrict__ wbt) {
  int m = blockIdx.x >> 6;
  int f = ((blockIdx.x & 63) << 8) + threadIdx.x;
  int n = f >> 7, k = f & 127;
  const float* src;
  switch (m) {
    case 0: src = wn; break;          // w_neigh[0]
    case 1: src = wl; break;          // w_loop[0]
    case 2: src = wn + 16384; break;  // w_neigh[1]
    case 3: src = wl + 16384; break;  // w_loop[1]
    default: src = tg; break;         // tg_w
  }
  wbt[m * 16384 + n * 128 + k] = f2b(src[k * 128 + n]);
}

// rel table f32 -> bf16
__global__ void convrel_kernel(const float* __restrict__ rel, u16* __restrict__ relb) {
  int i = blockIdx.x * 256 + threadIdx.x;  // 230*256 == 58880 exactly
  relb[i] = f2b(rel[i]);
}

// ---------- h0 = l2norm(emb_ent), f32 + bf16 ----------
__global__ void l2norm_kernel(const float* __restrict__ in, float* __restrict__ out,
                              u16* __restrict__ outb) {
  int row = blockIdx.x * 4 + (threadIdx.x >> 6);
  int lane = threadIdx.x & 63;
  size_t base = (size_t)row * H;
  float2 v = ((const float2*)(in + base))[lane];
  float ss = wave_sum(v.x * v.x + v.y * v.y);
  float inv = 1.0f / fmaxf(sqrtf(ss), 1e-12f);
  float2 o = {v.x * inv, v.y * inv};
  ((float2*)(out + base))[lane] = o;
  ushort2 ob; ob.x = f2b(o.x); ob.y = f2b(o.y);
  ((ushort2*)(outb + base))[lane] = ob;
}

// ---------- bucketed CSR build ----------
__global__ __launch_bounds__(256) void bucket_count(const int* __restrict__ dst,
                                                    int* __restrict__ bcnt) {
  int t = blockIdx.y;
  __shared__ int lc[NBUK];
  for (int j = threadIdx.x; j < NBUK; j += 256) lc[j] = 0;
  __syncthreads();
  for (int i = blockIdx.x * 256 + threadIdx.x; i < NEDGE; i += 64 * 256)
    atomicAdd(&lc[dst[(size_t)t * NEDGE + i] >> 7], 1);
  __syncthreads();
  for (int j = threadIdx.x; j < NBUK; j += 256)
    if (lc[j]) atomicAdd(&bcnt[t * NBUK + j], lc[j]);
}

__global__ __launch_bounds__(512) void bucket_scan(const int* __restrict__ bcnt,
                                                   int* __restrict__ bstart,
                                                   int* __restrict__ curA) {
  int t = blockIdx.x, tid = threadIdx.x;
  __shared__ int s[512];
  int v = (tid < NBUK) ? bcnt[t * NBUK + tid] : 0;
  s[tid] = v;
  __syncthreads();
  for (int off = 1; off < 512; off <<= 1) {
    int u = (tid >= off) ? s[tid - off] : 0;
    __syncthreads();
    s[tid] += u;
    __syncthreads();
  }
  if (tid < NBUK) {
    int ex = s[tid] - v;
    bstart[t * NBUK + tid] = ex;
    curA[t * NBUK + tid] = ex;
  }
}

// pass A (two-level): LDS bucket histogram -> chunked global reservation ->
// mostly-coalesced 8B scatter into reserved sub-ranges. All timesteps batched.
__global__ __launch_bounds__(256) void passA_kernel(const int* __restrict__ src,
                                                    const int* __restrict__ dst,
                                                    const int* __restrict__ ety,
                                                    int* curA, u64* __restrict__ tmp) {
  int t = blockIdx.y;
  __shared__ int cnt[NBUK], base[NBUK];
  for (int j = threadIdx.x; j < NBUK; j += 256) cnt[j] = 0;
  __syncthreads();
  int e0 = blockIdx.x * EPB;
  int e1 = e0 + EPB < NEDGE ? e0 + EPB : NEDGE;
  for (int i = e0 + threadIdx.x; i < e1; i += 256)
    atomicAdd(&cnt[dst[(size_t)t * NEDGE + i] >> 7], 1);
  __syncthreads();
  for (int j = threadIdx.x; j < NBUK; j += 256) {
    int c = cnt[j];
    base[j] = c ? atomicAdd(&curA[t * NBUK + j], c) : 0;
    cnt[j] = 0;  // becomes local cursor
  }
  __syncthreads();
  for (int i = e0 + threadIdx.x; i < e1; i += 256) {
    size_t o = (size_t)t * NEDGE + i;
    int d = dst[o];
    int j = d >> 7;
    int p = base[j] + atomicAdd(&cnt[j], 1);
    tmp[(size_t)t * NEDGE + p] = ((u64)d << 32) | (u32)src[o] | ((u32)ety[o] << 17);
  }
}

// pass B: one block per (bucket, t); per-dst counts+scan in LDS, write rp ends,
// scatter final 4B entries within the bucket's small window
__global__ __launch_bounds__(256) void passB_kernel(const u64* __restrict__ tmp,
                                                    const int* __restrict__ bstart,
                                                    int* __restrict__ rp,
                                                    u32* __restrict__ edges) {
  int t = blockIdx.y, b = blockIdx.x, tid = threadIdx.x;
  int start = bstart[t * NBUK + b];
  int end = (b + 1 < NBUK) ? bstart[t * NBUK + b + 1] : NEDGE;
  __shared__ int cnt[128], scn[128], cur[128];
  if (tid < 128) cnt[tid] = 0;
  __syncthreads();
  for (int i = start + tid; i < end; i += 256)
    atomicAdd(&cnt[(int)((tmp[(size_t)t * NEDGE + i] >> 32) & 127)], 1);
  __syncthreads();
  if (tid < 128) scn[tid] = cnt[tid];
  __syncthreads();
  for (int off = 1; off < 128; off <<= 1) {
    int u = (tid < 128 && tid >= off) ? scn[tid - off] : 0;
    __syncthreads();
    if (tid < 128) scn[tid] += u;
    __syncthreads();
  }
  if (tid < 128) {
    int rs = start + scn[tid] - cnt[tid];
    cur[tid] = rs;
    int gd = (b << 7) + tid;
    if (gd < N_ENT) rp[t * N_ENT + gd] = rs + cnt[tid];  // end-of-row
  }
  __syncthreads();
  for (int i = start + tid; i < end; i += 256) {
    u64 e = tmp[(size_t)t * NEDGE + i];
    int p = atomicAdd(&cur[(int)((e >> 32) & 127)], 1);
    edges[(size_t)t * NEDGE + p] = (u32)e;
  }
}

// ---------- agg[d] = (sum h[src]+rel[ty]) / max(deg,1), bf16 in/out ----------
// 16 lanes x ushort8 per row: 4 rows per wave, 8 outstanding 16B loads per lane
__global__ __launch_bounds__(256) void gather_kernel(const u16* __restrict__ hb,
                                                     const u16* __restrict__ relb,
                                                     const int* __restrict__ rp,
                                                     const u32* __restrict__ edges,
                                                     u16* __restrict__ aggb) {
  int d = blockIdx.x * 16 + (threadIdx.x >> 4);
  int q = threadIdx.x & 15;
  int start = d ? rp[d - 1] : 0, end = rp[d];
  float a[8] = {};
  int i = start;
  for (; i + 4 <= end; i += 4) {
    u32 e0 = edges[i], e1 = edges[i + 1], e2 = edges[i + 2], e3 = edges[i + 3];
    us8 h0 = *(const us8*)(hb + (size_t)(e0 & 0x1FFFF) * H + q * 8);
    us8 r0 = *(const us8*)(relb + (size_t)(e0 >> 17) * H + q * 8);
    us8 h1 = *(const us8*)(hb + (size_t)(e1 & 0x1FFFF) * H + q * 8);
    us8 r1 = *(const us8*)(relb + (size_t)(e1 >> 17) * H + q * 8);
    us8 h2 = *(const us8*)(hb + (size_t)(e2 & 0x1FFFF) * H + q * 8);
    us8 r2 = *(const us8*)(relb + (size_t)(e2 >> 17) * H + q * 8);
    us8 h3 = *(const us8*)(hb + (size_t)(e3 & 0x1FFFF) * H + q * 8);
    us8 r3 = *(const us8*)(relb + (size_t)(e3 >> 17) * H + q * 8);
#pragma unroll
    for (int j = 0; j < 8; j++)
      a[j] += (b2f(h0[j]) + b2f(r0[j])) + (b2f(h1[j]) + b2f(r1[j])) +
              (b2f(h2[j]) + b2f(r2[j])) + (b2f(h3[j]) + b2f(r3[j]));
  }
  for (; i < end; i++) {
    u32 e0 = edges[i];
    us8 h0 = *(const us8*)(hb + (size_t)(e0 & 0x1FFFF) * H + q * 8);
    us8 r0 = *(const us8*)(relb + (size_t)(e0 >> 17) * H + q * 8);
#pragma unroll
    for (int j = 0; j < 8; j++) a[j] += b2f(h0[j]) + b2f(r0[j]);
  }
  int deg = end - start;
  float nm = 1.0f / (float)(deg > 0 ? deg : 1);
  us8 o;
#pragma unroll
  for (int j = 0; j < 8; j++) o[j] = f2b(a[j] * nm);
  *(us8*)(aggb + (size_t)d * H + q * 8) = o;
}

// ---------- layer-0: hA = rrelu(agg@Wn0 + h@Wl0), bf16 out ----------
// deg==0 rows (agg==0) are recomputed inline as rrelu(h@We0) [folded fixup]
__global__ __launch_bounds__(256) void rgcn_gemm0(
    const u16* __restrict__ A1, const u16* __restrict__ A2,
    const u16* __restrict__ B1t, const u16* __restrict__ B2t,
    const float* __restrict__ We, const int* __restrict__ rp,
    u16* __restrict__ Cb) {
  int wave = threadIdx.x >> 6, lane = threadIdx.x & 63;
  int row0 = blockIdx.x * 64 + wave * 16;
  int ar = lane & 15, kg = lane >> 4;
  int arow = row0 + ar;
  if (arow >= N_ENT) arow = N_ENT - 1;
  bf16x8 a1[4], a2[4];
#pragma unroll
  for (int s = 0; s < 4; s++) {
    a1[s] = *(const bf16x8*)(A1 + (size_t)arow * H + s * 32 + kg * 8);
    a2[s] = *(const bf16x8*)(A2 + (size_t)arow * H + s * 32 + kg * 8);
  }
  f32x4 acc[8];
  f32x4 z = {0.f, 0.f, 0.f, 0.f};
#pragma unroll
  for (int n = 0; n < 8; n++) acc[n] = z;
#pragma unroll
  for (int n = 0; n < 8; n++) {
    const u16* b1p = B1t + (size_t)(n * 16 + ar) * H + kg * 8;
    const u16* b2p = B2t + (size_t)(n * 16 + ar) * H + kg * 8;
#pragma unroll
    for (int s = 0; s < 4; s++) {
      bf16x8 b1 = *(const bf16x8*)(b1p + s * 32);
      bf16x8 b2 = *(const bf16x8*)(b2p + s * 32);
      acc[n] = __builtin_amdgcn_mfma_f32_16x16x32_bf16(a1[s], b1, acc[n], 0, 0, 0);
      acc[n] = __builtin_amdgcn_mfma_f32_16x16x32_bf16(a2[s], b2, acc[n], 0, 0, 0);
    }
  }
#pragma unroll
  for (int r = 0; r < 4; r++) {
    int gr = row0 + kg * 4 + r;
    if (gr >= N_ENT) continue;
    int dg = rp[gr] - (gr ? rp[gr - 1] : 0);
    if (dg == 0) {  // rare: recompute rrelu(h @ We) for this row's 8 cols
      float s[8] = {};
      for (int k = 0; k < H; k++) {
        float hv = b2f(A2[(size_t)gr * H + k]);
#pragma unroll
        for (int n = 0; n < 8; n++)
          s[n] = fmaf(hv, We[(size_t)k * H + ar + n * 16], s[n]);
      }
#pragma unroll
      for (int n = 0; n < 8; n++) {
        float v = s[n] >= 0.f ? s[n] : SLOPE * s[n];
        Cb[(size_t)gr * H + ar + n * 16] = f2b(v);
      }
    } else {
#pragma unroll
      for (int n = 0; n < 8; n++) {
        float v = acc[n][r];
        v = v >= 0.f ? v : SLOPE * v;
        Cb[(size_t)gr * H + ar + n * 16] = f2b(v);
      }
    }
  }
}

// ---------- fused layer-1 GEMM + gate GEMM + rrelu + l2norm + combine ----------
// deg==0 rows recompute z = rrelu(hA@We1) inline before the l2norm [folded fixup]
__global__ __launch_bounds__(256) void step_final(
    const u16* __restrict__ aggb, const u16* __restrict__ hAb, const u16* hbio,
    const u16* __restrict__ B1t, const u16* __restrict__ B2t, const u16* __restrict__ B3t,
    const float* __restrict__ We, const int* __restrict__ rp,
    const float* __restrict__ tgb, const float* __restrict__ h_t, float* __restrict__ h_n,
    u16* hb_out) {
  int wave = threadIdx.x >> 6, lane = threadIdx.x & 63;
  int row0 = blockIdx.x * 64 + wave * 16;
  int ar = lane & 15, kg = lane >> 4;
  int arow = row0 + ar;
  if (arow >= N_ENT) arow = N_ENT - 1;
  bf16x8 a1[4], a2[4], a3[4];
#pragma unroll
  for (int s = 0; s < 4; s++) {
    a1[s] = *(const bf16x8*)(aggb + (size_t)arow * H + s * 32 + kg * 8);
    a2[s] = *(const bf16x8*)(hAb + (size_t)arow * H + s * 32 + kg * 8);
    a3[s] = *(const bf16x8*)(hbio + (size_t)arow * H + s * 32 + kg * 8);
  }
  f32x4 accm[8], accg[8];
  f32x4 z4 = {0.f, 0.f, 0.f, 0.f};
#pragma unroll
  for (int n = 0; n < 8; n++) { accm[n] = z4; accg[n] = z4; }
#pragma unroll
  for (int n = 0; n < 8; n++) {
    const u16* b1p = B1t + (size_t)(n * 16 + ar) * H + kg * 8;
    const u16* b2p = B2t + (size_t)(n * 16 + ar) * H + kg * 8;
    const u16* b3p = B3t + (size_t)(n * 16 + ar) * H + kg * 8;
#pragma unroll
    for (int s = 0; s < 4; s++) {
      bf16x8 b1 = *(const bf16x8*)(b1p + s * 32);
      bf16x8 b2 = *(const bf16x8*)(b2p + s * 32);
      bf16x8 b3 = *(const bf16x8*)(b3p + s * 32);
      accm[n] = __builtin_amdgcn_mfma_f32_16x16x32_bf16(a1[s], b1, accm[n], 0, 0, 0);
      accm[n] = __builtin_amdgcn_mfma_f32_16x16x32_bf16(a2[s], b2, accm[n], 0, 0, 0);
      accg[n] = __builtin_amdgcn_mfma_f32_16x16x32_bf16(a3[s], b3, accg[n], 0, 0, 0);
    }
  }
#pragma unroll
  for (int r = 0; r < 4; r++) {
    int grow = row0 + kg * 4 + r;
    bool ok = grow < N_ENT;
    int gsafe = ok ? grow : 0;
    int dg = ok ? (rp[gsafe] - (gsafe ? rp[gsafe - 1] : 0)) : 1;
    float zs[8], ssq = 0.f;
    if (dg == 0) {  // rare: z = rrelu(hA @ We1)
#pragma unroll
      for (int n = 0; n < 8; n++) zs[n] = 0.f;
      for (int k = 0; k < H; k++) {
        float hv = b2f(hAb[(size_t)grow * H + k]);
#pragma unroll
        for (int n = 0; n < 8; n++)
          zs[n] = fmaf(hv, We[(size_t)k * H + ar + n * 16], zs[n]);
      }
#pragma unroll
      for (int n = 0; n < 8; n++) {
        zs[n] = zs[n] >= 0.f ? zs[n] : SLOPE * zs[n];
        ssq += zs[n] * zs[n];
      }
    } else {
#pragma unroll
      for (int n = 0; n < 8; n++) {
        float v = accm[n][r];
        v = v >= 0.f ? v : SLOPE * v;
        zs[n] = v;
        ssq += v * v;
      }
    }
    ssq += __shfl_xor(ssq, 1, 64);
    ssq += __shfl_xor(ssq, 2, 64);
    ssq += __shfl_xor(ssq, 4, 64);
    ssq += __shfl_xor(ssq, 8, 64);
    float inv = 1.0f / fmaxf(sqrtf(ssq), 1e-12f);
#pragma unroll
    for (int n = 0; n < 8; n++) {
      int c = ar + n * 16;
      float g = 1.0f / (1.0f + expf(-(accg[n][r] + tgb[c])));
      float hp = ok ? h_t[(size_t)grow * H + c] : 0.f;
      float o = g * (zs[n] * inv) + (1.0f - g) * hp;
      if (ok) {
        h_n[(size_t)grow * H + c] = o;
        hb_out[(size_t)grow * H + c] = f2b(o);
      }
    }
  }
}

extern "C" void kernel_launch(void* const* d_in, const int* in_sizes, int n_in,
                              void* d_out, int out_size, void* d_ws, size_t ws_size,
                              hipStream_t stream) {
  const float* emb_ent  = (const float*)d_in[0];
  const float* emb_rel  = (const float*)d_in[1];
  const float* w_neigh  = (const float*)d_in[2];
  const float* w_loop   = (const float*)d_in[3];
  const float* w_evolve = (const float*)d_in[4];
  const float* tg_w     = (const float*)d_in[5];
  const float* tg_b     = (const float*)d_in[6];
  const int* src = (const int*)d_in[7];
  const int* dst = (const int*)d_in[8];
  const int* ety = (const int*)d_in[9];
  float* out = (float*)d_out;

  const size_t NH = (size_t)N_ENT * H;
  auto au = [](size_t x) { return (x + 255) & ~(size_t)255; };
  char* w = (char*)d_ws;
  int* rp8 = (int*)w;     w += au((size_t)T_STEPS * N_ENT * 4);
  int* bcnt = (int*)w;    w += au((size_t)T_STEPS * NBUK * 4);
  int* bstart = (int*)w;  w += au((size_t)T_STEPS * NBUK * 4);
  int* curA = (int*)w;    w += au((size_t)T_STEPS * NBUK * 4);
  u32* edges8 = (u32*)w;  w += au((size_t)T_STEPS * NEDGE * 4);
  // union: tmp (8*NEDGE*8 = 38.4MB) aliases aggb|hAb|hb (3*NH*2 = 38.4MB).
  // CSR build (writes+reads tmp) fully precedes l2norm (first hb write).
  char* uni = w;          w += au((size_t)T_STEPS * NEDGE * 8);
  u64* tmp = (u64*)uni;
  u16* aggb = (u16*)uni;
  u16* hAb = (u16*)(uni + NH * 2);
  u16* hb  = (u16*)(uni + NH * 4);
  u16* wbt = (u16*)w;     w += au((size_t)5 * 16384 * 2);
  u16* relb = (u16*)w;    w += au((size_t)NREL * H * 2);

  // ---- CSR build first (uses tmp region before aggb/hAb/hb alias it) ----
  hipMemsetAsync(bcnt, 0, (size_t)T_STEPS * NBUK * 4, stream);
  bucket_count<<<dim3(64, T_STEPS), 256, 0, stream>>>(dst, bcnt);
  bucket_scan<<<T_STEPS, 512, 0, stream>>>(bcnt, bstart, curA);
  passA_kernel<<<dim3((NEDGE + EPB - 1) / EPB, T_STEPS), 256, 0, stream>>>(
      src, dst, ety, curA, tmp);
  passB_kernel<<<dim3(NBUK, T_STEPS), 256, 0, stream>>>(tmp, bstart, rp8, edges8);

  // ---- conversions + h0 (hb now safe to write) ----
  hipMemcpyAsync(out + (size_t)(T_STEPS + 1) * NH, emb_rel, (size_t)NREL * H * 4,
                 hipMemcpyDeviceToDevice, stream);
  convw_kernel<<<320, 256, 0, stream>>>(w_neigh, w_loop, tg_w, wbt);
  convrel_kernel<<<230, 256, 0, stream>>>(emb_rel, relb);
  l2norm_kernel<<<N_ENT / 4, 256, 0, stream>>>(emb_ent, out, hb);

  for (int t = 0; t < T_STEPS; t++) {
    float* h_t = out + (size_t)t * NH;
    float* h_n = out + (size_t)(t + 1) * NH;
    const int* rp = rp8 + (size_t)t * N_ENT;
    const u32* edges = edges8 + (size_t)t * NEDGE;

    // layer 0 (fixup folded into epilogue)
    gather_kernel<<<N_ENT / 16, 256, 0, stream>>>(hb, relb, rp, edges, aggb);
    rgcn_gemm0<<<(N_ENT + 63) / 64, 256, 0, stream>>>(
        aggb, hb, wbt, wbt + 16384, w_evolve, rp, hAb);
    // layer 1 + gate + l2norm + combine (fixup folded)
    gather_kernel<<<N_ENT / 16, 256, 0, stream>>>(hAb, relb, rp, edges, aggb);
    step_final<<<(N_ENT + 63) / 64, 256, 0, stream>>>(
        aggb, hAb, hb, wbt + 32768, wbt + 49152, wbt + 65536,
        w_evolve + 16384, rp, tg_b, h_t, h_n, hb);
  }
}